// Round 3
// baseline (119.033 us; speedup 1.0000x reference)
//
#include <hip/hip_runtime.h>

// Pytorch3D-style barycentric attribute interpolation.
//   d_in[0]: pix_to_face (N,H,W,1) int32, -1 = background   [streaming, nt]
//   d_in[1]: bary_coords (N,H,W,1,3) float32                [streaming, nt]
//   d_in[2]: attributes  (N*F, 3, 3) float32 (~6 MB)        [cached gather]
// Output: (N, 3, H, W) float32, bg pixels = 0.              [streaming, nt]

#define HW_CONST (1024 * 1024)   // H*W, power of two

// clang native vectors — required by __builtin_nontemporal_*
typedef int   ivec4 __attribute__((ext_vector_type(4)));
typedef float fvec4 __attribute__((ext_vector_type(4)));

__global__ __launch_bounds__(256, 4) void rast_interp_kernel(
    const int*   __restrict__ p2f,
    const float* __restrict__ bary,
    const float* __restrict__ attrs,
    float*       __restrict__ out,
    int ngroups)   // number of 8-pixel groups
{
    const int stride = gridDim.x * blockDim.x;
    for (int g = blockIdx.x * blockDim.x + threadIdx.x; g < ngroups; g += stride) {
        const long long pix0 = (long long)g * 8;

        // ---- streaming loads, non-temporal (keep L2 for attrs) ----
        const ivec4* fptr = reinterpret_cast<const ivec4*>(p2f + pix0);
        const ivec4 fa = __builtin_nontemporal_load(fptr);
        const ivec4 fb = __builtin_nontemporal_load(fptr + 1);

        const fvec4* bptr = reinterpret_cast<const fvec4*>(bary + pix0 * 3);
        fvec4 b[6];
        #pragma unroll
        for (int i = 0; i < 6; ++i) b[i] = __builtin_nontemporal_load(bptr + i);

        float bf[24];
        #pragma unroll
        for (int i = 0; i < 6; ++i) {
            bf[4 * i + 0] = b[i].x; bf[4 * i + 1] = b[i].y;
            bf[4 * i + 2] = b[i].z; bf[4 * i + 3] = b[i].w;
        }
        const int fidx[8] = {fa.x, fa.y, fa.z, fa.w, fb.x, fb.y, fb.z, fb.w};

        // ---- gather + weighted sum (L2-cached random access) ----
        float v[3][8];
        #pragma unroll
        for (int j = 0; j < 8; ++j) {
            const int f = fidx[j];
            const float w0 = bf[3 * j], w1 = bf[3 * j + 1], w2 = bf[3 * j + 2];
            if (f >= 0) {
                const float* a = attrs + (size_t)f * 9;   // 3 verts x 3 ch
                #pragma unroll
                for (int d = 0; d < 3; ++d)
                    v[d][j] = w0 * a[d] + w1 * a[3 + d] + w2 * a[6 + d];
            } else {
                v[0][j] = 0.0f; v[1][j] = 0.0f; v[2][j] = 0.0f;
            }
        }

        // ---- streaming stores, non-temporal ----
        const int n  = (int)(pix0 >> 20);            // / (1024*1024)
        const int hw = (int)(pix0 & (HW_CONST - 1));
        float* obase = out + (size_t)n * 3 * HW_CONST + hw;
        #pragma unroll
        for (int d = 0; d < 3; ++d) {
            fvec4* op = reinterpret_cast<fvec4*>(obase + (size_t)d * HW_CONST);
            fvec4 lo = {v[d][0], v[d][1], v[d][2], v[d][3]};
            fvec4 hi = {v[d][4], v[d][5], v[d][6], v[d][7]};
            __builtin_nontemporal_store(lo, op);
            __builtin_nontemporal_store(hi, op + 1);
        }
    }
}

extern "C" void kernel_launch(void* const* d_in, const int* in_sizes, int n_in,
                              void* d_out, int out_size, void* d_ws, size_t ws_size,
                              hipStream_t stream) {
    const int*   p2f   = (const int*)d_in[0];
    const float* bary  = (const float*)d_in[1];
    const float* attrs = (const float*)d_in[2];
    float*       out   = (float*)d_out;

    const int npix    = in_sizes[0];      // N*H*W*K, K=1
    const int ngroups = npix / 8;

    const int block = 256;
    int grid = (ngroups + block - 1) / block;
    if (grid > 2048) grid = 2048;         // grid-stride the rest

    rast_interp_kernel<<<grid, block, 0, stream>>>(p2f, bary, attrs, out, ngroups);
}